// Round 1
// baseline (329.786 us; speedup 1.0000x reference)
//
#include <hip/hip_runtime.h>
#include <math.h>

#define E_THREADS 256

// RBF constants: OFFSET = linspace(-3,3,10), COEFF = -0.5/step^2 = -1.125
__device__ __constant__ float c_offs[10] = {
    -3.0f, -2.3333333f, -1.6666667f, -1.0f, -0.33333334f,
     0.33333334f, 1.0f, 1.6666667f, 2.3333333f, 3.0f
};

__global__ __launch_bounds__(E_THREADS)
void exchange_block_kernel(
    const int*   __restrict__ edge_src,
    const int*   __restrict__ edge_dst,
    const int*   __restrict__ batch_idx,
    const float* __restrict__ cell,
    const float* __restrict__ edge_shift,
    const float* __restrict__ pos,
    const float* __restrict__ angles,
    const float* __restrict__ cr_bonds,
    const float* __restrict__ ln_g,
    const float* __restrict__ ln_b,
    const float* __restrict__ wn1, const float* __restrict__ bn1,
    const float* __restrict__ wn2, const float* __restrict__ bn2,
    const float* __restrict__ we1, const float* __restrict__ be1,
    const float* __restrict__ we2, const float* __restrict__ be2,
    const float* __restrict__ wr1, const float* __restrict__ br1,
    const float* __restrict__ wr2, const float* __restrict__ br2,
    float* __restrict__ out, int E)
{
    // Transposed layer-1 weights: neuron-major rows of 60 (padded to 64 floats)
    // neurons 0..31  = normal head (wn1), 32..95 = extreme (we1), 96..127 = routing (wr1)
    __shared__ float WT1[128][64];
    __shared__ float B1[128];
    __shared__ float W2[128][2];
    __shared__ float LG[60], LB[60];

    for (int idx = threadIdx.x; idx < 128 * 64; idx += E_THREADS) {
        int i = idx >> 6;
        int k = idx & 63;
        float w = 0.0f;
        if (k < 60) {
            if (i < 32)       w = wn1[k * 32 + i];
            else if (i < 96)  w = we1[k * 64 + (i - 32)];
            else              w = wr1[k * 32 + (i - 96)];
        }
        WT1[i][k] = w;
    }
    if (threadIdx.x < 128) {
        int i = threadIdx.x;
        float b, w0, w1 = 0.0f;
        if (i < 32)      { b = bn1[i];      w0 = wn2[i]; }
        else if (i < 96) { b = be1[i - 32]; w0 = we2[i - 32]; }
        else             { b = br1[i - 96]; w0 = wr2[(i - 96) * 2 + 0];
                                            w1 = wr2[(i - 96) * 2 + 1]; }
        B1[i] = b; W2[i][0] = w0; W2[i][1] = w1;
    }
    if (threadIdx.x < 60) {
        LG[threadIdx.x] = ln_g[threadIdx.x];
        LB[threadIdx.x] = ln_b[threadIdx.x];
    }
    __syncthreads();

    int e = blockIdx.x * E_THREADS + threadIdx.x;
    if (e >= E) return;

    // ---- gather + geometry ----
    int s = edge_src[e];
    int d = edge_dst[e];
    int g = batch_idx[s];
    float sh0 = edge_shift[e * 3 + 0];
    float sh1 = edge_shift[e * 3 + 1];
    float sh2 = edge_shift[e * 3 + 2];
    const float* c = cell + g * 9;
    // tvec[j] = sum_i shift[i] * cell[i][j]
    float t0 = sh0 * c[0] + sh1 * c[3] + sh2 * c[6];
    float t1 = sh0 * c[1] + sh1 * c[4] + sh2 * c[7];
    float t2 = sh0 * c[2] + sh1 * c[5] + sh2 * c[8];
    float r0 = pos[d * 3 + 0] - pos[s * 3 + 0] + t0;
    float r1 = pos[d * 3 + 1] - pos[s * 3 + 1] + t1;
    float r2 = pos[d * 3 + 2] - pos[s * 3 + 2] + t2;
    float dist = sqrtf(r0 * r0 + r1 * r1 + r2 * r2);

    // ---- z-scores ----
    float distz = (dist - 4.0f) * (1.0f / 0.16f);
    float angz  = (angles[e] + 0.025f) * (1.0f / 0.06f);
    float l0 = (cr_bonds[e * 4 + 0] - 2.8f) * (1.0f / 0.035f);
    float l1 = (cr_bonds[e * 4 + 1] - 2.8f) * (1.0f / 0.035f);
    float l2 = (cr_bonds[e * 4 + 2] - 2.8f) * (1.0f / 0.035f);
    float l3 = (cr_bonds[e * 4 + 3] - 2.8f) * (1.0f / 0.035f);

    // ---- RBF embedding: 6 groups x 10 basis ----
    float h[60];
    #pragma unroll
    for (int k = 0; k < 10; ++k) {
        float o = c_offs[k];
        float d0 = distz - o; h[k]      = __expf(-1.125f * d0 * d0);
        float d1 = angz  - o; h[10 + k] = __expf(-1.125f * d1 * d1);
        float d2 = l0    - o; h[20 + k] = __expf(-1.125f * d2 * d2);
        float d3 = l1    - o; h[30 + k] = __expf(-1.125f * d3 * d3);
        float d4 = l2    - o; h[40 + k] = __expf(-1.125f * d4 * d4);
        float d5 = l3    - o; h[50 + k] = __expf(-1.125f * d5 * d5);
    }

    // ---- LayerNorm over 60 ----
    float mu = 0.0f;
    #pragma unroll
    for (int k = 0; k < 60; ++k) mu += h[k];
    mu *= (1.0f / 60.0f);
    float var = 0.0f;
    #pragma unroll
    for (int k = 0; k < 60; ++k) { float xc = h[k] - mu; var += xc * xc; }
    var *= (1.0f / 60.0f);
    float rs = rsqrtf(var + 1e-5f);
    #pragma unroll
    for (int k = 0; k < 60; ++k) h[k] = (h[k] - mu) * rs * LG[k] + LB[k];

    // ---- three heads, layer1 (128 fused neurons) + layer2 on the fly ----
    float accN = 0.0f, accE = 0.0f, rr0 = 0.0f, rr1 = 0.0f;
    for (int i = 0; i < 128; ++i) {
        const float4* row = (const float4*)(&WT1[i][0]);
        float a0 = B1[i], a1 = 0.0f, a2 = 0.0f, a3 = 0.0f;
        #pragma unroll
        for (int j = 0; j < 15; ++j) {
            float4 w = row[j];
            a0 += h[4 * j + 0] * w.x;
            a1 += h[4 * j + 1] * w.y;
            a2 += h[4 * j + 2] * w.z;
            a3 += h[4 * j + 3] * w.w;
        }
        float a = (a0 + a1) + (a2 + a3);
        a = a / (1.0f + __expf(-a));     // silu
        float w0 = W2[i][0];
        if (i < 32)       accN += a * w0;
        else if (i < 96)  accE += a * w0;
        else              { rr0 += a * w0; rr1 += a * W2[i][1]; }
    }
    accN += bn2[0];
    accE += be2[0];
    rr0  += br2[0];
    rr1  += br2[1];

    // softmax over 2 -> sigmoid form
    float route0 = 1.0f / (1.0f + __expf(rr1 - rr0));
    out[e] = route0 * accN + (1.0f - route0) * accE;
}

extern "C" void kernel_launch(void* const* d_in, const int* in_sizes, int n_in,
                              void* d_out, int out_size, void* d_ws, size_t ws_size,
                              hipStream_t stream)
{
    const int*   edge_src  = (const int*)  d_in[0];
    const int*   edge_dst  = (const int*)  d_in[1];
    const int*   batch_idx = (const int*)  d_in[2];
    const float* cell      = (const float*)d_in[3];
    const float* edge_shift= (const float*)d_in[4];
    const float* pos       = (const float*)d_in[5];
    const float* angles    = (const float*)d_in[6];
    const float* cr_bonds  = (const float*)d_in[7];
    const float* ln_g      = (const float*)d_in[8];
    const float* ln_b      = (const float*)d_in[9];
    const float* wn1 = (const float*)d_in[10]; const float* bn1 = (const float*)d_in[11];
    const float* wn2 = (const float*)d_in[12]; const float* bn2 = (const float*)d_in[13];
    const float* we1 = (const float*)d_in[14]; const float* be1 = (const float*)d_in[15];
    const float* we2 = (const float*)d_in[16]; const float* be2 = (const float*)d_in[17];
    const float* wr1 = (const float*)d_in[18]; const float* br1 = (const float*)d_in[19];
    const float* wr2 = (const float*)d_in[20]; const float* br2 = (const float*)d_in[21];

    int E = in_sizes[0];
    float* out = (float*)d_out;

    int grid = (E + E_THREADS - 1) / E_THREADS;
    hipLaunchKernelGGL(exchange_block_kernel, dim3(grid), dim3(E_THREADS), 0, stream,
                       edge_src, edge_dst, batch_idx, cell, edge_shift, pos,
                       angles, cr_bonds, ln_g, ln_b,
                       wn1, bn1, wn2, bn2, we1, be1, we2, be2,
                       wr1, br1, wr2, br2, out, E);
}

// Round 2
// 163.795 us; speedup vs baseline: 2.0134x; 2.0134x over previous
//
#include <hip/hip_runtime.h>
#include <math.h>

#define E_THREADS 256
#define EPB 256   // edges per block

typedef __attribute__((ext_vector_type(8))) short short8;
typedef __attribute__((ext_vector_type(4))) float floatx4;

__device__ __constant__ float c_offs[10] = {
    -3.0f, -2.3333333f, -1.6666667f, -1.0f, -0.33333334f,
     0.33333334f, 1.0f, 1.6666667f, 2.3333333f, 3.0f
};

__device__ inline unsigned short f2bf(float f) {
    union { float f; unsigned u; } v; v.f = f;
    unsigned r = v.u + 0x7FFFu + ((v.u >> 16) & 1u);
    return (unsigned short)(r >> 16);
}

__device__ inline float fsilu(float x) { return x / (1.0f + __expf(-x)); }

__global__ __launch_bounds__(E_THREADS)
void exchange_block_kernel(
    const int*   __restrict__ edge_src,
    const int*   __restrict__ edge_dst,
    const int*   __restrict__ batch_idx,
    const float* __restrict__ cell,
    const float* __restrict__ edge_shift,
    const float* __restrict__ pos,
    const float* __restrict__ angles,
    const float* __restrict__ cr_bonds,
    const float* __restrict__ ln_g,
    const float* __restrict__ ln_b,
    const float* __restrict__ wn1, const float* __restrict__ bn1,
    const float* __restrict__ wn2, const float* __restrict__ bn2,
    const float* __restrict__ we1, const float* __restrict__ be1,
    const float* __restrict__ we2, const float* __restrict__ be2,
    const float* __restrict__ wr1, const float* __restrict__ br1,
    const float* __restrict__ wr2, const float* __restrict__ br2,
    float* __restrict__ out, int E)
{
    // HLDS: [256 edges][64 k] bf16, XOR-swizzled 16B chunks  (32 KB)
    // WLDS: [128 neurons][64 k] bf16, same swizzle           (16 KB)
    __shared__ __align__(16) unsigned short HLDS[EPB * 64];
    __shared__ __align__(16) unsigned short WLDS[128 * 64];
    __shared__ float B1s[128], W2As[128], W2Bs[128];
    __shared__ float LG[60], LB[60];

    const int tid = threadIdx.x;

    // ---- stage transposed fused layer-1 weights (neurons 0..31=N, 32..95=E, 96..127=R) ----
    for (int idx = tid; idx < 128 * 64; idx += E_THREADS) {
        int n = idx >> 6, k = idx & 63;
        float w = 0.0f;
        if (k < 60) {
            if (n < 32)       w = wn1[k * 32 + n];
            else if (n < 96)  w = we1[k * 64 + (n - 32)];
            else              w = wr1[k * 32 + (n - 96)];
        }
        int byte = n * 128 + ((k * 2) ^ ((n & 7) << 4));
        *(unsigned short*)((char*)WLDS + byte) = f2bf(w);
    }
    if (tid < 128) {
        int n = tid;
        float b, w0, w1 = 0.0f;
        if (n < 32)      { b = bn1[n];      w0 = wn2[n]; }
        else if (n < 96) { b = be1[n - 32]; w0 = we2[n - 32]; }
        else             { b = br1[n - 96]; w0 = wr2[(n - 96) * 2 + 0];
                                            w1 = wr2[(n - 96) * 2 + 1]; }
        B1s[n] = b; W2As[n] = w0; W2Bs[n] = w1;
    }
    if (tid < 60) { LG[tid] = ln_g[tid]; LB[tid] = ln_b[tid]; }

    // ---- phase 1: per-lane RBF + LayerNorm -> bf16 tile in LDS ----
    const int row = tid;
    const int e = blockIdx.x * EPB + tid;
    float h[64];
    if (e < E) {
        int s = edge_src[e];
        int d = edge_dst[e];
        int g = batch_idx[s];
        float sh0 = edge_shift[e * 3 + 0];
        float sh1 = edge_shift[e * 3 + 1];
        float sh2 = edge_shift[e * 3 + 2];
        const float* c = cell + g * 9;
        float t0 = sh0 * c[0] + sh1 * c[3] + sh2 * c[6];
        float t1 = sh0 * c[1] + sh1 * c[4] + sh2 * c[7];
        float t2 = sh0 * c[2] + sh1 * c[5] + sh2 * c[8];
        float r0 = pos[d * 3 + 0] - pos[s * 3 + 0] + t0;
        float r1 = pos[d * 3 + 1] - pos[s * 3 + 1] + t1;
        float r2 = pos[d * 3 + 2] - pos[s * 3 + 2] + t2;
        float dist = sqrtf(r0 * r0 + r1 * r1 + r2 * r2);

        float z0 = (dist - 4.0f) * (1.0f / 0.16f);
        float z1 = (angles[e] + 0.025f) * (1.0f / 0.06f);
        float l0 = (cr_bonds[e * 4 + 0] - 2.8f) * (1.0f / 0.035f);
        float l1 = (cr_bonds[e * 4 + 1] - 2.8f) * (1.0f / 0.035f);
        float l2 = (cr_bonds[e * 4 + 2] - 2.8f) * (1.0f / 0.035f);
        float l3 = (cr_bonds[e * 4 + 3] - 2.8f) * (1.0f / 0.035f);

        #pragma unroll
        for (int k = 0; k < 10; ++k) {
            float o = c_offs[k];
            float d0 = z0 - o; h[k]      = __expf(-1.125f * d0 * d0);
            float d1 = z1 - o; h[10 + k] = __expf(-1.125f * d1 * d1);
            float d2 = l0 - o; h[20 + k] = __expf(-1.125f * d2 * d2);
            float d3 = l1 - o; h[30 + k] = __expf(-1.125f * d3 * d3);
            float d4 = l2 - o; h[40 + k] = __expf(-1.125f * d4 * d4);
            float d5 = l3 - o; h[50 + k] = __expf(-1.125f * d5 * d5);
        }
        float mu = 0.0f;
        #pragma unroll
        for (int k = 0; k < 60; ++k) mu += h[k];
        mu *= (1.0f / 60.0f);
        float var = 0.0f;
        #pragma unroll
        for (int k = 0; k < 60; ++k) { float xc = h[k] - mu; var += xc * xc; }
        var *= (1.0f / 60.0f);
        float rs = rsqrtf(var + 1e-5f);
        // LG/LB staged by this thread group earlier in this same pre-barrier
        // region; LG/LB writes above are by the same warp pattern (tid<60) —
        // need them visible: they were written before phase 1 by lower tids,
        // but not synchronized. Use global ln_g/ln_b directly instead (cached).
        #pragma unroll
        for (int k = 0; k < 60; ++k) h[k] = (h[k] - mu) * rs * ln_g[k] + ln_b[k];
        #pragma unroll
        for (int k = 60; k < 64; ++k) h[k] = 0.0f;
    } else {
        #pragma unroll
        for (int k = 0; k < 64; ++k) h[k] = 0.0f;
    }

    {
        const int swz = (row & 7) << 4;
        #pragma unroll
        for (int c = 0; c < 8; ++c) {
            unsigned p0 = (unsigned)f2bf(h[8 * c + 0]) | ((unsigned)f2bf(h[8 * c + 1]) << 16);
            unsigned p1 = (unsigned)f2bf(h[8 * c + 2]) | ((unsigned)f2bf(h[8 * c + 3]) << 16);
            unsigned p2 = (unsigned)f2bf(h[8 * c + 4]) | ((unsigned)f2bf(h[8 * c + 5]) << 16);
            unsigned p3 = (unsigned)f2bf(h[8 * c + 6]) | ((unsigned)f2bf(h[8 * c + 7]) << 16);
            uint4 pk = make_uint4(p0, p1, p2, p3);
            *(uint4*)((char*)HLDS + row * 128 + ((c * 16) ^ swz)) = pk;
        }
    }
    __syncthreads();

    // ---- phase 2: MFMA GEMM  [64 edges/wave] x [k=64] x [128 neurons] ----
    const int lane = tid & 63;
    const int wv   = tid >> 6;
    const int lrow = lane & 15;        // m (edge-in-tile) for A, n-in-tile for B/C
    const int khi  = lane >> 4;        // 0..3
    const int kof  = khi * 16;         // byte offset of this lane's 8-bf16 k-chunk within 64B K-step
    const int swz  = (lrow & 7) << 4;

    // B fragments to registers: 8 N-tiles x 2 K-steps
    short8 bfrag[8][2];
    #pragma unroll
    for (int u = 0; u < 8; ++u) {
        const char* base = (const char*)WLDS + (16 * u + lrow) * 128;
        #pragma unroll
        for (int s = 0; s < 2; ++s)
            bfrag[u][s] = *(const short8*)(base + ((s * 64 + kof) ^ swz));
    }

    // per-lane layer-2 weights / biases
    float w2a[8], w2b0, w2b1;
    #pragma unroll
    for (int u = 0; u < 8; ++u) w2a[u] = W2As[16 * u + lrow];
    w2b0 = W2Bs[96 + lrow];
    w2b1 = W2Bs[112 + lrow];
    float b1v[8];
    #pragma unroll
    for (int u = 0; u < 8; ++u) b1v[u] = B1s[16 * u + lrow];

    const float bn2v = bn2[0], be2v = be2[0], br2v0 = br2[0], br2v1 = br2[1];

    #pragma unroll
    for (int t = 0; t < 4; ++t) {
        const int arow = wv * 64 + t * 16 + lrow;
        const char* abase = (const char*)HLDS + arow * 128;
        short8 a0 = *(const short8*)(abase + ((0  + kof) ^ swz));
        short8 a1 = *(const short8*)(abase + ((64 + kof) ^ swz));

        floatx4 acc[8];
        #pragma unroll
        for (int u = 0; u < 8; ++u) {
            float b = b1v[u];
            acc[u] = (floatx4){b, b, b, b};
            acc[u] = __builtin_amdgcn_mfma_f32_16x16x32_bf16(a0, bfrag[u][0], acc[u], 0, 0, 0);
            acc[u] = __builtin_amdgcn_mfma_f32_16x16x32_bf16(a1, bfrag[u][1], acc[u], 0, 0, 0);
        }

        // ---- epilogue: silu, layer-2, head reduce over 16 lanes, routing ----
        float o4[4];
        #pragma unroll
        for (int j = 0; j < 4; ++j) {
            float sN = 0.0f, sE = 0.0f, sR0 = 0.0f, sR1 = 0.0f;
            #pragma unroll
            for (int u = 0; u < 8; ++u) {
                float a  = acc[u][j];
                float sl = fsilu(a);
                float w  = w2a[u];
                if (u < 2)      sN += sl * w;
                else if (u < 6) sE += sl * w;
                else {
                    sR0 += sl * w;
                    sR1 += sl * ((u == 6) ? w2b0 : w2b1);
                }
            }
            #pragma unroll
            for (int m = 1; m < 16; m <<= 1) {
                sN  += __shfl_xor(sN,  m);
                sE  += __shfl_xor(sE,  m);
                sR0 += __shfl_xor(sR0, m);
                sR1 += __shfl_xor(sR1, m);
            }
            sN += bn2v; sE += be2v; sR0 += br2v0; sR1 += br2v1;
            float rt = 1.0f / (1.0f + __expf(sR1 - sR0));
            o4[j] = rt * sN + (1.0f - rt) * sE;
        }
        if (lrow == 0) {
            int eb = blockIdx.x * EPB + wv * 64 + t * 16 + khi * 4;
            if (eb < E)
                *(float4*)(out + eb) = make_float4(o4[0], o4[1], o4[2], o4[3]);
        }
    }
}

extern "C" void kernel_launch(void* const* d_in, const int* in_sizes, int n_in,
                              void* d_out, int out_size, void* d_ws, size_t ws_size,
                              hipStream_t stream)
{
    const int*   edge_src  = (const int*)  d_in[0];
    const int*   edge_dst  = (const int*)  d_in[1];
    const int*   batch_idx = (const int*)  d_in[2];
    const float* cell      = (const float*)d_in[3];
    const float* edge_shift= (const float*)d_in[4];
    const float* pos       = (const float*)d_in[5];
    const float* angles    = (const float*)d_in[6];
    const float* cr_bonds  = (const float*)d_in[7];
    const float* ln_g      = (const float*)d_in[8];
    const float* ln_b      = (const float*)d_in[9];
    const float* wn1 = (const float*)d_in[10]; const float* bn1 = (const float*)d_in[11];
    const float* wn2 = (const float*)d_in[12]; const float* bn2 = (const float*)d_in[13];
    const float* we1 = (const float*)d_in[14]; const float* be1 = (const float*)d_in[15];
    const float* we2 = (const float*)d_in[16]; const float* be2 = (const float*)d_in[17];
    const float* wr1 = (const float*)d_in[18]; const float* br1 = (const float*)d_in[19];
    const float* wr2 = (const float*)d_in[20]; const float* br2 = (const float*)d_in[21];

    int E = in_sizes[0];
    float* out = (float*)d_out;

    int grid = (E + EPB - 1) / EPB;
    hipLaunchKernelGGL(exchange_block_kernel, dim3(grid), dim3(E_THREADS), 0, stream,
                       edge_src, edge_dst, batch_idx, cell, edge_shift, pos,
                       angles, cr_bonds, ln_g, ln_b,
                       wn1, bn1, wn2, bn2, we1, be1, we2, be2,
                       wr1, br1, wr2, br2, out, E);
}

// Round 3
// 142.631 us; speedup vs baseline: 2.3122x; 1.1484x over previous
//
#include <hip/hip_runtime.h>
#include <math.h>

#define E_THREADS 256
#define EPB 256   // edges per block

typedef __attribute__((ext_vector_type(8))) short short8;
typedef __attribute__((ext_vector_type(4))) float floatx4;

// RBF as exp2 of quadratic: exp(-1.125 (z-o)^2) = exp2(A*z^2 + B_k*z + C_k)
// A = -1.125*log2(e) = -1.6232946;  B_k = -2*A*o_k; C_k = A*o_k^2
__device__ __constant__ float c_B[10] = {
    -9.7397680f, -7.5753751f, -5.4109822f, -3.2465893f, -1.0821964f,
     1.0821964f,  3.2465893f,  5.4109822f,  7.5753751f,  9.7397680f
};
__device__ __constant__ float c_C[10] = {
    -14.609652f, -8.8378534f, -4.5091519f, -1.6232946f, -0.18036607f,
    -0.18036607f, -1.6232946f, -4.5091519f, -8.8378534f, -14.609652f
};

__device__ inline unsigned short f2bf(float f) {
    union { float f; unsigned u; } v; v.f = f;
    unsigned r = v.u + 0x7FFFu + ((v.u >> 16) & 1u);
    return (unsigned short)(r >> 16);
}

__device__ inline unsigned cvt_pk_bf16(float lo, float hi) {
    unsigned r;
    asm("v_cvt_pk_bf16_f32 %0, %1, %2" : "=v"(r) : "v"(lo), "v"(hi));
    return r;
}

__device__ inline float fexp2(float x) { return __builtin_amdgcn_exp2f(x); }
__device__ inline float frcp(float x)  { return __builtin_amdgcn_rcpf(x); }
#define LOG2E 1.44269504f

__global__ __launch_bounds__(E_THREADS)
void exchange_block_kernel(
    const int*   __restrict__ edge_src,
    const int*   __restrict__ edge_dst,
    const int*   __restrict__ batch_idx,
    const float* __restrict__ cell,
    const float* __restrict__ edge_shift,
    const float* __restrict__ pos,
    const float* __restrict__ angles,
    const float* __restrict__ cr_bonds,
    const float* __restrict__ ln_g,
    const float* __restrict__ ln_b,
    const float* __restrict__ wn1, const float* __restrict__ bn1,
    const float* __restrict__ wn2, const float* __restrict__ bn2,
    const float* __restrict__ we1, const float* __restrict__ be1,
    const float* __restrict__ we2, const float* __restrict__ be2,
    const float* __restrict__ wr1, const float* __restrict__ br1,
    const float* __restrict__ wr2, const float* __restrict__ br2,
    float* __restrict__ out, int E)
{
    // HLDS: [256 edges][64 k] bf16 XOR-swizzled (32 KB); k=60 column == 1.0 (bias)
    // WLDS: [128 neurons][64 k] bf16 same swizzle (16 KB); k=60 row == bias b1[n]
    __shared__ __align__(16) unsigned short HLDS[EPB * 64];
    __shared__ __align__(16) unsigned short WLDS[128 * 64];
    __shared__ float W2As[128], W2Bs[128];

    const int tid = threadIdx.x;

    // ---- stage fused layer-1 weights (n: 0..31=N, 32..95=E, 96..127=R) + bias col ----
    for (int idx = tid; idx < 128 * 64; idx += E_THREADS) {
        int n = idx >> 6, k = idx & 63;
        float w = 0.0f;
        if (k < 60) {
            if (n < 32)       w = wn1[k * 32 + n];
            else if (n < 96)  w = we1[k * 64 + (n - 32)];
            else              w = wr1[k * 32 + (n - 96)];
        } else if (k == 60) {
            if (n < 32)       w = bn1[n];
            else if (n < 96)  w = be1[n - 32];
            else              w = br1[n - 96];
        }
        int byte = n * 128 + ((k * 2) ^ ((n & 7) << 4));
        *(unsigned short*)((char*)WLDS + byte) = f2bf(w);
    }
    if (tid < 128) {
        int n = tid;
        float w0, w1 = 0.0f;
        if (n < 32)      { w0 = wn2[n]; }
        else if (n < 96) { w0 = we2[n - 32]; }
        else             { w0 = wr2[(n - 96) * 2 + 0];
                           w1 = wr2[(n - 96) * 2 + 1]; }
        W2As[n] = w0; W2Bs[n] = w1;
    }

    // ---- phase 1: per-lane RBF + LayerNorm -> bf16 tile in LDS ----
    const int row = tid;
    const int e = blockIdx.x * EPB + tid;
    float h[64];
    if (e < E) {
        int s = edge_src[e];
        int d = edge_dst[e];
        int g = batch_idx[s];
        float sh0 = edge_shift[e * 3 + 0];
        float sh1 = edge_shift[e * 3 + 1];
        float sh2 = edge_shift[e * 3 + 2];
        const float* c = cell + g * 9;
        float t0 = sh0 * c[0] + sh1 * c[3] + sh2 * c[6];
        float t1 = sh0 * c[1] + sh1 * c[4] + sh2 * c[7];
        float t2 = sh0 * c[2] + sh1 * c[5] + sh2 * c[8];
        float r0 = pos[d * 3 + 0] - pos[s * 3 + 0] + t0;
        float r1 = pos[d * 3 + 1] - pos[s * 3 + 1] + t1;
        float r2 = pos[d * 3 + 2] - pos[s * 3 + 2] + t2;
        float dist = sqrtf(r0 * r0 + r1 * r1 + r2 * r2);

        float z[6];
        z[0] = (dist - 4.0f) * (1.0f / 0.16f);
        z[1] = (angles[e] + 0.025f) * (1.0f / 0.06f);
        z[2] = (cr_bonds[e * 4 + 0] - 2.8f) * (1.0f / 0.035f);
        z[3] = (cr_bonds[e * 4 + 1] - 2.8f) * (1.0f / 0.035f);
        z[4] = (cr_bonds[e * 4 + 2] - 2.8f) * (1.0f / 0.035f);
        z[5] = (cr_bonds[e * 4 + 3] - 2.8f) * (1.0f / 0.035f);

        #pragma unroll
        for (int gi = 0; gi < 6; ++gi) {
            float zv = z[gi];
            float az2 = -1.6232946f * zv * zv;
            #pragma unroll
            for (int k = 0; k < 10; ++k)
                h[gi * 10 + k] = fexp2(az2 + fmaf(zv, c_B[k], c_C[k]));
        }
        float mu = 0.0f;
        #pragma unroll
        for (int k = 0; k < 60; ++k) mu += h[k];
        mu *= (1.0f / 60.0f);
        float var = 0.0f;
        #pragma unroll
        for (int k = 0; k < 60; ++k) { float xc = h[k] - mu; var += xc * xc; }
        var *= (1.0f / 60.0f);
        float rs = rsqrtf(var + 1e-5f);
        #pragma unroll
        for (int k = 0; k < 60; ++k) h[k] = (h[k] - mu) * rs * ln_g[k] + ln_b[k];
    } else {
        #pragma unroll
        for (int k = 0; k < 60; ++k) h[k] = 0.0f;
    }
    h[60] = 1.0f;   // bias column
    h[61] = 0.0f; h[62] = 0.0f; h[63] = 0.0f;

    {
        const int swz = (row & 7) << 4;
        #pragma unroll
        for (int c = 0; c < 8; ++c) {
            unsigned q0 = cvt_pk_bf16(h[8 * c + 0], h[8 * c + 1]);
            unsigned q1 = cvt_pk_bf16(h[8 * c + 2], h[8 * c + 3]);
            unsigned q2 = cvt_pk_bf16(h[8 * c + 4], h[8 * c + 5]);
            unsigned q3 = cvt_pk_bf16(h[8 * c + 6], h[8 * c + 7]);
            *(uint4*)((char*)HLDS + row * 128 + ((c * 16) ^ swz)) = make_uint4(q0, q1, q2, q3);
        }
    }
    __syncthreads();

    // ---- phase 2: MFMA  C[n][edge] = W[n][k] * H^T[k][edge] ----
    const int lane = tid & 63;
    const int wv   = tid >> 6;
    const int lcol = lane & 15;        // edge-in-tile (B/C col), n-in-tile (A row)
    const int khi  = lane >> 4;        // k-slice selector
    const int kof  = khi * 16;
    const int aswz = (lcol & 7) << 4;  // (16u+lcol)&7 == lcol&7

    // per-lane layer-2 weights: this lane's 32 neurons are n = 16u + khi*4 + j
    float4 w2v[8];
    #pragma unroll
    for (int u = 0; u < 8; ++u) w2v[u] = *(float4*)&W2As[16 * u + khi * 4];
    float4 w2b6 = *(float4*)&W2Bs[96  + khi * 4];
    float4 w2b7 = *(float4*)&W2Bs[112 + khi * 4];

    const float bn2v = bn2[0], be2v = be2[0], br2v0 = br2[0], br2v1 = br2[1];

    #pragma unroll
    for (int t = 0; t < 4; ++t) {
        const int hrow = wv * 64 + t * 16 + lcol;
        const char* hbase = (const char*)HLDS + hrow * 128;
        const int hswz = (hrow & 7) << 4;
        short8 b0 = *(const short8*)(hbase + ((0  + kof) ^ hswz));
        short8 b1 = *(const short8*)(hbase + ((64 + kof) ^ hswz));

        float sN = 0.0f, sE = 0.0f, sR0 = 0.0f, sR1 = 0.0f;
        #pragma unroll
        for (int u = 0; u < 8; ++u) {
            const char* abase = (const char*)WLDS + (16 * u + lcol) * 128;
            short8 a0 = *(const short8*)(abase + ((0  + kof) ^ aswz));
            short8 a1 = *(const short8*)(abase + ((64 + kof) ^ aswz));
            floatx4 acc = (floatx4){0.0f, 0.0f, 0.0f, 0.0f};
            acc = __builtin_amdgcn_mfma_f32_16x16x32_bf16(a0, b0, acc, 0, 0, 0);
            acc = __builtin_amdgcn_mfma_f32_16x16x32_bf16(a1, b1, acc, 0, 0, 0);

            // silu + layer-2 partial sums (in-register; n = 16u + khi*4 + j)
            #pragma unroll
            for (int j = 0; j < 4; ++j) {
                float a  = acc[j];
                float sl = a * frcp(1.0f + fexp2(a * -LOG2E));
                float w  = (j == 0) ? w2v[u].x : (j == 1) ? w2v[u].y
                         : (j == 2) ? w2v[u].z : w2v[u].w;
                if (u < 2)      sN += sl * w;
                else if (u < 6) sE += sl * w;
                else {
                    float wb = (u == 6)
                        ? ((j == 0) ? w2b6.x : (j == 1) ? w2b6.y : (j == 2) ? w2b6.z : w2b6.w)
                        : ((j == 0) ? w2b7.x : (j == 1) ? w2b7.y : (j == 2) ? w2b7.z : w2b7.w);
                    sR0 += sl * w;
                    sR1 += sl * wb;
                }
            }
        }
        // reduce across the 4 khi groups (lanes e, e+16, e+32, e+48)
        sN  += __shfl_xor(sN,  16); sN  += __shfl_xor(sN,  32);
        sE  += __shfl_xor(sE,  16); sE  += __shfl_xor(sE,  32);
        sR0 += __shfl_xor(sR0, 16); sR0 += __shfl_xor(sR0, 32);
        sR1 += __shfl_xor(sR1, 16); sR1 += __shfl_xor(sR1, 32);

        sN += bn2v; sE += be2v; sR0 += br2v0; sR1 += br2v1;
        float rt = frcp(1.0f + fexp2((sR1 - sR0) * LOG2E));  // sigmoid(sR0-sR1)
        float val = sE + rt * (sN - sE);

        if (lane < 16) {
            int eb = blockIdx.x * EPB + wv * 64 + t * 16 + lcol;
            if (eb < E) out[eb] = val;
        }
    }
}

extern "C" void kernel_launch(void* const* d_in, const int* in_sizes, int n_in,
                              void* d_out, int out_size, void* d_ws, size_t ws_size,
                              hipStream_t stream)
{
    const int*   edge_src  = (const int*)  d_in[0];
    const int*   edge_dst  = (const int*)  d_in[1];
    const int*   batch_idx = (const int*)  d_in[2];
    const float* cell      = (const float*)d_in[3];
    const float* edge_shift= (const float*)d_in[4];
    const float* pos       = (const float*)d_in[5];
    const float* angles    = (const float*)d_in[6];
    const float* cr_bonds  = (const float*)d_in[7];
    const float* ln_g      = (const float*)d_in[8];
    const float* ln_b      = (const float*)d_in[9];
    const float* wn1 = (const float*)d_in[10]; const float* bn1 = (const float*)d_in[11];
    const float* wn2 = (const float*)d_in[12]; const float* bn2 = (const float*)d_in[13];
    const float* we1 = (const float*)d_in[14]; const float* be1 = (const float*)d_in[15];
    const float* we2 = (const float*)d_in[16]; const float* be2 = (const float*)d_in[17];
    const float* wr1 = (const float*)d_in[18]; const float* br1 = (const float*)d_in[19];
    const float* wr2 = (const float*)d_in[20]; const float* br2 = (const float*)d_in[21];

    int E = in_sizes[0];
    float* out = (float*)d_out;

    int grid = (E + EPB - 1) / EPB;
    hipLaunchKernelGGL(exchange_block_kernel, dim3(grid), dim3(E_THREADS), 0, stream,
                       edge_src, edge_dst, batch_idx, cell, edge_shift, pos,
                       angles, cr_bonds, ln_g, ln_b,
                       wn1, bn1, wn2, bn2, we1, be1, we2, be2,
                       wr1, br1, wr2, br2, out, E);
}

// Round 4
// 103.638 us; speedup vs baseline: 3.1821x; 1.3762x over previous
//
#include <hip/hip_runtime.h>
#include <math.h>

#define E_THREADS 256
#define EPB 256   // edges per block

typedef __attribute__((ext_vector_type(8))) short short8;
typedef __attribute__((ext_vector_type(4))) float floatx4;

// ws layout (26640 bytes used):
//   [0,     16384)  WF  : 1024 x uint4  — per-lane MFMA A-fragments (8 bf16 each)
//                         entry (u*2+s)*64 + lane  holds W'[n=16u+(lane&15)][k=s*32+(lane>>4)*8 .. +8]
//                         (k==60 row = LN-folded bias; k>60 = 0)
//   [16384, 24576)  W2A : 512 x float4  — entry u*64+lane = W2a[16u+(lane>>4)*4 .. +4]
//   [24576, 26624)  W2B : 128 x float4  — entry i*64+lane = W2b[96+16i+(lane>>4)*4 .. +4]
//   [26624, 26640)  SC  : 4 floats      — bn2, be2, br2[0], br2[1]

// RBF as exp2 of quadratic: exp(-1.125 (z-o)^2) = exp2(A*z^2 + B_k*z + C_k)
__device__ __constant__ float c_B[10] = {
    -9.7397680f, -7.5753751f, -5.4109822f, -3.2465893f, -1.0821964f,
     1.0821964f,  3.2465893f,  5.4109822f,  7.5753751f,  9.7397680f
};
__device__ __constant__ float c_C[10] = {
    -14.609652f, -8.8378534f, -4.5091519f, -1.6232946f, -0.18036607f,
    -0.18036607f, -1.6232946f, -4.5091519f, -8.8378534f, -14.609652f
};

__device__ inline unsigned short f2bf(float f) {
    union { float f; unsigned u; } v; v.f = f;
    unsigned r = v.u + 0x7FFFu + ((v.u >> 16) & 1u);
    return (unsigned short)(r >> 16);
}

__device__ inline unsigned cvt_pk_bf16(float lo, float hi) {
    unsigned r;
    asm("v_cvt_pk_bf16_f32 %0, %1, %2" : "=v"(r) : "v"(lo), "v"(hi));
    return r;
}

__device__ inline float fexp2(float x) { return __builtin_amdgcn_exp2f(x); }
__device__ inline float frcp(float x)  { return __builtin_amdgcn_rcpf(x); }
#define LOG2E 1.44269504f

__global__ __launch_bounds__(256)
void prep_weights(
    const float* __restrict__ ln_g, const float* __restrict__ ln_b,
    const float* __restrict__ wn1, const float* __restrict__ bn1,
    const float* __restrict__ wn2, const float* __restrict__ bn2,
    const float* __restrict__ we1, const float* __restrict__ be1,
    const float* __restrict__ we2, const float* __restrict__ be2,
    const float* __restrict__ wr1, const float* __restrict__ br1,
    const float* __restrict__ wr2, const float* __restrict__ br2,
    char* __restrict__ ws)
{
    uint4*  WF  = (uint4*)ws;
    float4* W2A = (float4*)(ws + 16384);
    float4* W2B = (float4*)(ws + 24576);
    float*  SC  = (float*)(ws + 26624);
    const int tid = threadIdx.x;

    // ---- A fragments (LN affine folded: W' = g*W, bias row = b1 + W^T b_ln) ----
    for (int idx = tid; idx < 1024; idx += 256) {
        int u = idx >> 7, s = (idx >> 6) & 1, lane = idx & 63;
        int lcol = lane & 15, khi = lane >> 4;
        int n = 16 * u + lcol;
        int kbase = s * 32 + khi * 8;
        float w8[8];
        for (int j = 0; j < 8; ++j) {
            int k = kbase + j;
            float w = 0.0f;
            if (k < 60) {
                float wv = (n < 32) ? wn1[k * 32 + n]
                         : (n < 96) ? we1[k * 64 + (n - 32)]
                                    : wr1[k * 32 + (n - 96)];
                w = ln_g[k] * wv;
            } else if (k == 60) {
                float b = (n < 32) ? bn1[n] : (n < 96) ? be1[n - 32] : br1[n - 96];
                for (int kk = 0; kk < 60; ++kk) {
                    float wv = (n < 32) ? wn1[kk * 32 + n]
                             : (n < 96) ? we1[kk * 64 + (n - 32)]
                                        : wr1[kk * 32 + (n - 96)];
                    b += ln_b[kk] * wv;
                }
                w = b;
            }
            w8[j] = w;
        }
        unsigned q0 = (unsigned)f2bf(w8[0]) | ((unsigned)f2bf(w8[1]) << 16);
        unsigned q1 = (unsigned)f2bf(w8[2]) | ((unsigned)f2bf(w8[3]) << 16);
        unsigned q2 = (unsigned)f2bf(w8[4]) | ((unsigned)f2bf(w8[5]) << 16);
        unsigned q3 = (unsigned)f2bf(w8[6]) | ((unsigned)f2bf(w8[7]) << 16);
        WF[idx] = make_uint4(q0, q1, q2, q3);
    }
    // ---- layer-2 weight fragments ----
    for (int idx = tid; idx < 512; idx += 256) {
        int u = idx >> 6, lane = idx & 63, khi = lane >> 4;
        int n0 = 16 * u + khi * 4;
        float4 v; float* pv = (float*)&v;
        for (int j = 0; j < 4; ++j) {
            int n = n0 + j;
            pv[j] = (n < 32) ? wn2[n] : (n < 96) ? we2[n - 32] : wr2[(n - 96) * 2];
        }
        W2A[idx] = v;
    }
    for (int idx = tid; idx < 128; idx += 256) {
        int i = idx >> 6, lane = idx & 63, khi = lane >> 4;
        int n0 = 96 + 16 * i + khi * 4;
        float4 v; float* pv = (float*)&v;
        for (int j = 0; j < 4; ++j) pv[j] = wr2[(n0 + j - 96) * 2 + 1];
        W2B[idx] = v;
    }
    if (tid == 0) { SC[0] = bn2[0]; SC[1] = be2[0]; SC[2] = br2[0]; SC[3] = br2[1]; }
}

__global__ __launch_bounds__(E_THREADS, 4)
void exchange_block_kernel(
    const int*   __restrict__ edge_src,
    const int*   __restrict__ edge_dst,
    const int*   __restrict__ batch_idx,
    const float* __restrict__ cell,
    const float* __restrict__ edge_shift,
    const float* __restrict__ pos,
    const float* __restrict__ angles,
    const float* __restrict__ cr_bonds,
    const char*  __restrict__ ws,
    float* __restrict__ out, int E)
{
    __shared__ __align__(16) unsigned short HLDS[EPB * 64];   // exactly 32768 B

    const int tid = threadIdx.x;
    const int e = blockIdx.x * EPB + tid;

    // ---- phase 1: RBF + LayerNorm (affine folded into weights) ----
    float h[64];
    if (e < E) {
        int s = edge_src[e];
        int d = edge_dst[e];
        int g = batch_idx[s];
        float sh0 = edge_shift[e * 3 + 0];
        float sh1 = edge_shift[e * 3 + 1];
        float sh2 = edge_shift[e * 3 + 2];
        const float* c = cell + g * 9;
        float t0 = sh0 * c[0] + sh1 * c[3] + sh2 * c[6];
        float t1 = sh0 * c[1] + sh1 * c[4] + sh2 * c[7];
        float t2 = sh0 * c[2] + sh1 * c[5] + sh2 * c[8];
        float r0 = pos[d * 3 + 0] - pos[s * 3 + 0] + t0;
        float r1 = pos[d * 3 + 1] - pos[s * 3 + 1] + t1;
        float r2 = pos[d * 3 + 2] - pos[s * 3 + 2] + t2;
        float dist = sqrtf(r0 * r0 + r1 * r1 + r2 * r2);

        float z[6];
        z[0] = (dist - 4.0f) * (1.0f / 0.16f);
        z[1] = (angles[e] + 0.025f) * (1.0f / 0.06f);
        z[2] = (cr_bonds[e * 4 + 0] - 2.8f) * (1.0f / 0.035f);
        z[3] = (cr_bonds[e * 4 + 1] - 2.8f) * (1.0f / 0.035f);
        z[4] = (cr_bonds[e * 4 + 2] - 2.8f) * (1.0f / 0.035f);
        z[5] = (cr_bonds[e * 4 + 3] - 2.8f) * (1.0f / 0.035f);

        #pragma unroll
        for (int gi = 0; gi < 6; ++gi) {
            float zv = z[gi];
            float az2 = -1.6232946f * zv * zv;
            #pragma unroll
            for (int k = 0; k < 10; ++k)
                h[gi * 10 + k] = fexp2(az2 + fmaf(zv, c_B[k], c_C[k]));
        }
        float mu = 0.0f;
        #pragma unroll
        for (int k = 0; k < 60; ++k) mu += h[k];
        mu *= (1.0f / 60.0f);
        float var = 0.0f;
        #pragma unroll
        for (int k = 0; k < 60; ++k) { float xc = h[k] - mu; var += xc * xc; }
        var *= (1.0f / 60.0f);
        float rs = rsqrtf(var + 1e-5f);
        float nmurs = -mu * rs;
        #pragma unroll
        for (int k = 0; k < 60; ++k) h[k] = fmaf(h[k], rs, nmurs);
    } else {
        #pragma unroll
        for (int k = 0; k < 60; ++k) h[k] = 0.0f;
    }
    h[60] = 1.0f;   // bias column
    h[61] = 0.0f; h[62] = 0.0f; h[63] = 0.0f;

    {
        const int swz = (tid & 7) << 4;
        #pragma unroll
        for (int c = 0; c < 8; ++c) {
            unsigned q0 = cvt_pk_bf16(h[8 * c + 0], h[8 * c + 1]);
            unsigned q1 = cvt_pk_bf16(h[8 * c + 2], h[8 * c + 3]);
            unsigned q2 = cvt_pk_bf16(h[8 * c + 4], h[8 * c + 5]);
            unsigned q3 = cvt_pk_bf16(h[8 * c + 6], h[8 * c + 7]);
            *(uint4*)((char*)HLDS + tid * 128 + ((c * 16) ^ swz)) = make_uint4(q0, q1, q2, q3);
        }
    }
    __syncthreads();

    // ---- phase 2: MFMA  C[n][edge] = W'[n][k] * H^T[k][edge] + fused epilogue ----
    const uint4*  WF  = (const uint4*)ws;
    const float4* W2A = (const float4*)(ws + 16384);
    const float4* W2B = (const float4*)(ws + 24576);
    const float*  SC  = (const float*)(ws + 26624);

    const int lane = tid & 63;
    const int wv   = tid >> 6;
    const int lcol = lane & 15;
    const int khi  = lane >> 4;
    const int kof  = khi * 16;

    uint4 wf[16];
    #pragma unroll
    for (int i = 0; i < 16; ++i) wf[i] = WF[i * 64 + lane];

    const float bn2v = SC[0], be2v = SC[1], br2v0 = SC[2], br2v1 = SC[3];

    #pragma unroll
    for (int t = 0; t < 4; ++t) {
        const int hrow = wv * 64 + t * 16 + lcol;
        const char* hbase = (const char*)HLDS + hrow * 128;
        const int hswz = (hrow & 7) << 4;
        short8 b0 = *(const short8*)(hbase + ((0  + kof) ^ hswz));
        short8 b1 = *(const short8*)(hbase + ((64 + kof) ^ hswz));

        float sN = 0.0f, sE = 0.0f, sR0 = 0.0f, sR1 = 0.0f;
        #pragma unroll
        for (int u = 0; u < 8; ++u) {
            short8 a0 = *(const short8*)&wf[u * 2 + 0];
            short8 a1 = *(const short8*)&wf[u * 2 + 1];
            floatx4 acc = (floatx4){0.0f, 0.0f, 0.0f, 0.0f};
            acc = __builtin_amdgcn_mfma_f32_16x16x32_bf16(a0, b0, acc, 0, 0, 0);
            acc = __builtin_amdgcn_mfma_f32_16x16x32_bf16(a1, b1, acc, 0, 0, 0);

            float4 w2 = W2A[u * 64 + lane];
            const float* w2p = (const float*)&w2;
            #pragma unroll
            for (int j = 0; j < 4; ++j) {
                float a  = acc[j];
                float sl = a * frcp(1.0f + fexp2(a * -LOG2E));
                float w  = w2p[j];
                if (u < 2)      sN += sl * w;
                else if (u < 6) sE += sl * w;
                else {
                    float4 wb4 = W2B[(u - 6) * 64 + lane];
                    sR0 += sl * w;
                    sR1 += sl * ((const float*)&wb4)[j];
                }
            }
        }
        // reduce across the 4 khi groups
        sN  += __shfl_xor(sN,  16); sN  += __shfl_xor(sN,  32);
        sE  += __shfl_xor(sE,  16); sE  += __shfl_xor(sE,  32);
        sR0 += __shfl_xor(sR0, 16); sR0 += __shfl_xor(sR0, 32);
        sR1 += __shfl_xor(sR1, 16); sR1 += __shfl_xor(sR1, 32);

        sN += bn2v; sE += be2v; sR0 += br2v0; sR1 += br2v1;
        float rt = frcp(1.0f + fexp2((sR1 - sR0) * LOG2E));   // sigmoid(sR0-sR1)
        float val = sE + rt * (sN - sE);

        if (lane < 16) {
            int eb = blockIdx.x * EPB + wv * 64 + t * 16 + lcol;
            if (eb < E) out[eb] = val;
        }
    }
}

extern "C" void kernel_launch(void* const* d_in, const int* in_sizes, int n_in,
                              void* d_out, int out_size, void* d_ws, size_t ws_size,
                              hipStream_t stream)
{
    const int*   edge_src  = (const int*)  d_in[0];
    const int*   edge_dst  = (const int*)  d_in[1];
    const int*   batch_idx = (const int*)  d_in[2];
    const float* cell      = (const float*)d_in[3];
    const float* edge_shift= (const float*)d_in[4];
    const float* pos       = (const float*)d_in[5];
    const float* angles    = (const float*)d_in[6];
    const float* cr_bonds  = (const float*)d_in[7];
    const float* ln_g      = (const float*)d_in[8];
    const float* ln_b      = (const float*)d_in[9];
    const float* wn1 = (const float*)d_in[10]; const float* bn1 = (const float*)d_in[11];
    const float* wn2 = (const float*)d_in[12]; const float* bn2 = (const float*)d_in[13];
    const float* we1 = (const float*)d_in[14]; const float* be1 = (const float*)d_in[15];
    const float* we2 = (const float*)d_in[16]; const float* be2 = (const float*)d_in[17];
    const float* wr1 = (const float*)d_in[18]; const float* br1 = (const float*)d_in[19];
    const float* wr2 = (const float*)d_in[20]; const float* br2 = (const float*)d_in[21];

    int E = in_sizes[0];
    float* out = (float*)d_out;

    hipLaunchKernelGGL(prep_weights, dim3(1), dim3(256), 0, stream,
                       ln_g, ln_b, wn1, bn1, wn2, bn2, we1, be1, we2, be2,
                       wr1, br1, wr2, br2, (char*)d_ws);

    int grid = (E + EPB - 1) / EPB;
    hipLaunchKernelGGL(exchange_block_kernel, dim3(grid), dim3(E_THREADS), 0, stream,
                       edge_src, edge_dst, batch_idx, cell, edge_shift, pos,
                       angles, cr_bonds, (const char*)d_ws, out, E);
}

// Round 5
// 82.185 us; speedup vs baseline: 4.0127x; 1.2610x over previous
//
#include <hip/hip_runtime.h>
#include <math.h>

#define E_THREADS 256
#define EPB 256   // edges per block

typedef __attribute__((ext_vector_type(8))) short short8;
typedef __attribute__((ext_vector_type(4))) float floatx4;

// ws layout:
//   [0,     16384)  WF  : 1024 x uint4 — per-lane MFMA A-fragments (8 bf16 each)
//                         entry (u*2+s)*64 + lane holds W'[n=16u+(lane&15)][k=s*32+(lane>>4)*8 ..+8]
//                         (k==60 row = LN-folded bias; k>60 = 0)
//   [16384, 16896)  W2A : 128 floats — layer-2 weight (head col 0) for fused neuron n
//   [16896, 17024)  W2B : 32 floats  — routing col-1 weights for n=96..127
//   [17024, 17040)  SC  : 4 floats   — bn2, be2, br2[0], br2[1]

// RBF as exp2 of quadratic: exp(-1.125 (z-o)^2) = exp2(A*z^2 + B_k*z + C_k)
__device__ __constant__ float c_B[10] = {
    -9.7397680f, -7.5753751f, -5.4109822f, -3.2465893f, -1.0821964f,
     1.0821964f,  3.2465893f,  5.4109822f,  7.5753751f,  9.7397680f
};
__device__ __constant__ float c_C[10] = {
    -14.609652f, -8.8378534f, -4.5091519f, -1.6232946f, -0.18036607f,
    -0.18036607f, -1.6232946f, -4.5091519f, -8.8378534f, -14.609652f
};

__device__ inline unsigned short f2bf(float f) {
    union { float f; unsigned u; } v; v.f = f;
    unsigned r = v.u + 0x7FFFu + ((v.u >> 16) & 1u);
    return (unsigned short)(r >> 16);
}

__device__ inline unsigned cvt_pk_bf16(float lo, float hi) {
    unsigned r;
    asm("v_cvt_pk_bf16_f32 %0, %1, %2" : "=v"(r) : "v"(lo), "v"(hi));
    return r;
}

__device__ inline float fexp2(float x) { return __builtin_amdgcn_exp2f(x); }
__device__ inline float frcp(float x)  { return __builtin_amdgcn_rcpf(x); }
#define LOG2E 1.44269504f

__global__ __launch_bounds__(256)
void prep_weights(
    const float* __restrict__ ln_g, const float* __restrict__ ln_b,
    const float* __restrict__ wn1, const float* __restrict__ bn1,
    const float* __restrict__ wn2, const float* __restrict__ bn2,
    const float* __restrict__ we1, const float* __restrict__ be1,
    const float* __restrict__ we2, const float* __restrict__ be2,
    const float* __restrict__ wr1, const float* __restrict__ br1,
    const float* __restrict__ wr2, const float* __restrict__ br2,
    char* __restrict__ ws)
{
    uint4* WF  = (uint4*)ws;
    float* W2A = (float*)(ws + 16384);
    float* W2B = (float*)(ws + 16896);
    float* SC  = (float*)(ws + 17024);
    const int tid = threadIdx.x;

    // ---- A fragments (LN affine folded: W' = g*W, bias row = b1 + W^T b_ln) ----
    for (int idx = tid; idx < 1024; idx += 256) {
        int u = idx >> 7, s = (idx >> 6) & 1, lane = idx & 63;
        int lcol = lane & 15, khi = lane >> 4;
        int n = 16 * u + lcol;
        int kbase = s * 32 + khi * 8;
        float w8[8];
        for (int j = 0; j < 8; ++j) {
            int k = kbase + j;
            float w = 0.0f;
            if (k < 60) {
                float wv = (n < 32) ? wn1[k * 32 + n]
                         : (n < 96) ? we1[k * 64 + (n - 32)]
                                    : wr1[k * 32 + (n - 96)];
                w = ln_g[k] * wv;
            } else if (k == 60) {
                float b = (n < 32) ? bn1[n] : (n < 96) ? be1[n - 32] : br1[n - 96];
                for (int kk = 0; kk < 60; ++kk) {
                    float wv = (n < 32) ? wn1[kk * 32 + n]
                             : (n < 96) ? we1[kk * 64 + (n - 32)]
                                        : wr1[kk * 32 + (n - 96)];
                    b += ln_b[kk] * wv;
                }
                w = b;
            }
            w8[j] = w;
        }
        unsigned q0 = (unsigned)f2bf(w8[0]) | ((unsigned)f2bf(w8[1]) << 16);
        unsigned q1 = (unsigned)f2bf(w8[2]) | ((unsigned)f2bf(w8[3]) << 16);
        unsigned q2 = (unsigned)f2bf(w8[4]) | ((unsigned)f2bf(w8[5]) << 16);
        unsigned q3 = (unsigned)f2bf(w8[6]) | ((unsigned)f2bf(w8[7]) << 16);
        WF[idx] = make_uint4(q0, q1, q2, q3);
    }
    // ---- layer-2 weights, plain layout ----
    if (tid < 128) {
        int n = tid;
        W2A[n] = (n < 32) ? wn2[n] : (n < 96) ? we2[n - 32] : wr2[(n - 96) * 2];
    }
    if (tid >= 128 && tid < 160) W2B[tid - 128] = wr2[(tid - 128) * 2 + 1];
    if (tid == 0) { SC[0] = bn2[0]; SC[1] = be2[0]; SC[2] = br2[0]; SC[3] = br2[1]; }
}

__attribute__((amdgpu_waves_per_eu(4, 4)))
__global__ __launch_bounds__(E_THREADS, 4)
void exchange_block_kernel(
    const int*   __restrict__ edge_src,
    const int*   __restrict__ edge_dst,
    const int*   __restrict__ batch_idx,
    const float* __restrict__ cell,
    const float* __restrict__ edge_shift,
    const float* __restrict__ pos,
    const float* __restrict__ angles,
    const float* __restrict__ cr_bonds,
    const char*  __restrict__ ws,
    float* __restrict__ out, int E)
{
    __shared__ __align__(16) unsigned short HLDS[EPB * 64];   // 32768 B
    __shared__ __align__(16) float LW2A[128];                 // 512 B
    __shared__ __align__(16) float LW2B[32];                  // 128 B

    const int tid = threadIdx.x;
    const int e = blockIdx.x * EPB + tid;

    // stage tiny layer-2 tables
    if (tid < 128)                LW2A[tid] = ((const float*)(ws + 16384))[tid];
    else if (tid < 160)           LW2B[tid - 128] = ((const float*)(ws + 16896))[tid - 128];

    // ---- phase 1: RBF + LayerNorm (affine folded into weights) ----
    float h[64];
    if (e < E) {
        int s = edge_src[e];
        int d = edge_dst[e];
        int g = batch_idx[s];
        float sh0 = edge_shift[e * 3 + 0];
        float sh1 = edge_shift[e * 3 + 1];
        float sh2 = edge_shift[e * 3 + 2];
        const float* c = cell + g * 9;
        float t0 = sh0 * c[0] + sh1 * c[3] + sh2 * c[6];
        float t1 = sh0 * c[1] + sh1 * c[4] + sh2 * c[7];
        float t2 = sh0 * c[2] + sh1 * c[5] + sh2 * c[8];
        float r0 = pos[d * 3 + 0] - pos[s * 3 + 0] + t0;
        float r1 = pos[d * 3 + 1] - pos[s * 3 + 1] + t1;
        float r2 = pos[d * 3 + 2] - pos[s * 3 + 2] + t2;
        float dist = sqrtf(r0 * r0 + r1 * r1 + r2 * r2);

        float z[6];
        z[0] = (dist - 4.0f) * (1.0f / 0.16f);
        z[1] = (angles[e] + 0.025f) * (1.0f / 0.06f);
        z[2] = (cr_bonds[e * 4 + 0] - 2.8f) * (1.0f / 0.035f);
        z[3] = (cr_bonds[e * 4 + 1] - 2.8f) * (1.0f / 0.035f);
        z[4] = (cr_bonds[e * 4 + 2] - 2.8f) * (1.0f / 0.035f);
        z[5] = (cr_bonds[e * 4 + 3] - 2.8f) * (1.0f / 0.035f);

        #pragma unroll
        for (int gi = 0; gi < 6; ++gi) {
            float zv = z[gi];
            float az2 = -1.6232946f * zv * zv;
            #pragma unroll
            for (int k = 0; k < 10; ++k)
                h[gi * 10 + k] = fexp2(az2 + fmaf(zv, c_B[k], c_C[k]));
        }
        float mu = 0.0f;
        #pragma unroll
        for (int k = 0; k < 60; ++k) mu += h[k];
        mu *= (1.0f / 60.0f);
        float var = 0.0f;
        #pragma unroll
        for (int k = 0; k < 60; ++k) { float xc = h[k] - mu; var += xc * xc; }
        var *= (1.0f / 60.0f);
        float rs = rsqrtf(var + 1e-5f);
        float nmurs = -mu * rs;
        #pragma unroll
        for (int k = 0; k < 60; ++k) h[k] = fmaf(h[k], rs, nmurs);
    } else {
        #pragma unroll
        for (int k = 0; k < 60; ++k) h[k] = 0.0f;
    }
    h[60] = 1.0f;   // bias column
    h[61] = 0.0f; h[62] = 0.0f; h[63] = 0.0f;

    {
        const int swz = (tid & 7) << 4;
        #pragma unroll
        for (int c = 0; c < 8; ++c) {
            unsigned q0 = cvt_pk_bf16(h[8 * c + 0], h[8 * c + 1]);
            unsigned q1 = cvt_pk_bf16(h[8 * c + 2], h[8 * c + 3]);
            unsigned q2 = cvt_pk_bf16(h[8 * c + 4], h[8 * c + 5]);
            unsigned q3 = cvt_pk_bf16(h[8 * c + 6], h[8 * c + 7]);
            *(uint4*)((char*)HLDS + tid * 128 + ((c * 16) ^ swz)) = make_uint4(q0, q1, q2, q3);
        }
    }
    __syncthreads();

    // ---- phase 2: MFMA  C[n][edge] = W'[n][k] * H^T[k][edge] + fused epilogue ----
    const uint4* WF = (const uint4*)ws;
    const float* SC = (const float*)(ws + 17024);

    const int lane = tid & 63;
    const int wv   = tid >> 6;
    const int lcol = lane & 15;
    const int khi  = lane >> 4;
    const int kof  = khi * 16;

    uint4 wf[16];
    #pragma unroll
    for (int i = 0; i < 16; ++i) wf[i] = WF[i * 64 + lane];

    const float bn2v = SC[0], be2v = SC[1], br2v0 = SC[2], br2v1 = SC[3];

    #pragma unroll
    for (int t = 0; t < 4; ++t) {
        const int hrow = wv * 64 + t * 16 + lcol;
        const char* hbase = (const char*)HLDS + hrow * 128;
        const int hswz = (hrow & 7) << 4;
        short8 b0 = *(const short8*)(hbase + ((0  + kof) ^ hswz));
        short8 b1 = *(const short8*)(hbase + ((64 + kof) ^ hswz));

        float sN = 0.0f, sE = 0.0f, sR0 = 0.0f, sR1 = 0.0f;
        #pragma unroll
        for (int u = 0; u < 8; ++u) {
            short8 a0 = *(const short8*)&wf[u * 2 + 0];
            short8 a1 = *(const short8*)&wf[u * 2 + 1];
            floatx4 acc = (floatx4){0.0f, 0.0f, 0.0f, 0.0f};
            acc = __builtin_amdgcn_mfma_f32_16x16x32_bf16(a0, b0, acc, 0, 0, 0);
            acc = __builtin_amdgcn_mfma_f32_16x16x32_bf16(a1, b1, acc, 0, 0, 0);

            // broadcast reads: all 16 lanes of a khi-group hit the same float4
            float4 w2 = *(const float4*)&LW2A[16 * u + khi * 4];
            const float* w2p = (const float*)&w2;
            float4 wb4;
            const float* wbp = (const float*)&wb4;
            if (u >= 6) wb4 = *(const float4*)&LW2B[(u - 6) * 16 + khi * 4];
            #pragma unroll
            for (int j = 0; j < 4; ++j) {
                float a  = acc[j];
                float sl = a * frcp(1.0f + fexp2(a * -LOG2E));
                float w  = w2p[j];
                if (u < 2)      sN += sl * w;
                else if (u < 6) sE += sl * w;
                else {
                    sR0 += sl * w;
                    sR1 += sl * wbp[j];
                }
            }
        }
        // reduce across the 4 khi groups
        sN  += __shfl_xor(sN,  16); sN  += __shfl_xor(sN,  32);
        sE  += __shfl_xor(sE,  16); sE  += __shfl_xor(sE,  32);
        sR0 += __shfl_xor(sR0, 16); sR0 += __shfl_xor(sR0, 32);
        sR1 += __shfl_xor(sR1, 16); sR1 += __shfl_xor(sR1, 32);

        sN += bn2v; sE += be2v; sR0 += br2v0; sR1 += br2v1;
        float rt = frcp(1.0f + fexp2((sR1 - sR0) * LOG2E));   // sigmoid(sR0-sR1)
        float val = sE + rt * (sN - sE);

        if (lane < 16) {
            int eb = blockIdx.x * EPB + wv * 64 + t * 16 + lcol;
            if (eb < E) out[eb] = val;
        }
    }
}

extern "C" void kernel_launch(void* const* d_in, const int* in_sizes, int n_in,
                              void* d_out, int out_size, void* d_ws, size_t ws_size,
                              hipStream_t stream)
{
    const int*   edge_src  = (const int*)  d_in[0];
    const int*   edge_dst  = (const int*)  d_in[1];
    const int*   batch_idx = (const int*)  d_in[2];
    const float* cell      = (const float*)d_in[3];
    const float* edge_shift= (const float*)d_in[4];
    const float* pos       = (const float*)d_in[5];
    const float* angles    = (const float*)d_in[6];
    const float* cr_bonds  = (const float*)d_in[7];
    const float* ln_g      = (const float*)d_in[8];
    const float* ln_b      = (const float*)d_in[9];
    const float* wn1 = (const float*)d_in[10]; const float* bn1 = (const float*)d_in[11];
    const float* wn2 = (const float*)d_in[12]; const float* bn2 = (const float*)d_in[13];
    const float* we1 = (const float*)d_in[14]; const float* be1 = (const float*)d_in[15];
    const float* we2 = (const float*)d_in[16]; const float* be2 = (const float*)d_in[17];
    const float* wr1 = (const float*)d_in[18]; const float* br1 = (const float*)d_in[19];
    const float* wr2 = (const float*)d_in[20]; const float* br2 = (const float*)d_in[21];

    int E = in_sizes[0];
    float* out = (float*)d_out;

    hipLaunchKernelGGL(prep_weights, dim3(1), dim3(256), 0, stream,
                       ln_g, ln_b, wn1, bn1, wn2, bn2, we1, be1, we2, be2,
                       wr1, br1, wr2, br2, (char*)d_ws);

    int grid = (E + EPB - 1) / EPB;
    hipLaunchKernelGGL(exchange_block_kernel, dim3(grid), dim3(E_THREADS), 0, stream,
                       edge_src, edge_dst, batch_idx, cell, edge_shift, pos,
                       angles, cr_bonds, (const char*)d_ws, out, E);
}